// Round 13
// baseline (518.705 us; speedup 1.0000x reference)
//
#include <hip/hip_runtime.h>
#include <hip/hip_bf16.h>

typedef __hip_bfloat16 bf16;
typedef unsigned char u8;
typedef __attribute__((ext_vector_type(4))) float f32x4;
typedef __attribute__((ext_vector_type(2))) float f32x2;
typedef __attribute__((ext_vector_type(8))) int i32x8;
typedef __attribute__((ext_vector_type(4))) unsigned int u32x4;

struct L4 { long a, b, c, d; };
struct U2 { u32x4 x, y; };

// async global->LDS 16B copy; LDS dst must be wave-uniform base + lane*16
typedef __attribute__((address_space(3))) unsigned int lds_uint;
typedef __attribute__((address_space(1))) const unsigned int g_uint;
__device__ inline void gload_lds16(const void* g, void* l) {
    __builtin_amdgcn_global_load_lds((g_uint*)g, (lds_uint*)l, 16, 0, 0);
}

__device__ inline void block_reduce_atomic(float v, float* dst) {
    #pragma unroll
    for (int o = 32; o > 0; o >>= 1) v += __shfl_down(v, o, 64);
    __shared__ float ws[8];
    const int lane = threadIdx.x & 63;
    const int wid  = threadIdx.x >> 6;
    if (lane == 0) ws[wid] = v;
    __syncthreads();
    if (threadIdx.x == 0) {
        float s = 0.f;
        const int nw = (blockDim.x + 63) >> 6;
        for (int i = 0; i < nw; ++i) s += ws[i];
        atomicAdd(dst, s);
    }
}

// ---------------------------------------------------------------------------
// prep: zero accumulators + repack all three conv weights to MX layout
// per 32ch phase p: [t(0..7)][q(16ch half)][CO][16B] then tap8 [q][CO][16B]
// ---------------------------------------------------------------------------
__global__ void prep_kernel(const float* __restrict__ w2, u8* __restrict__ wb2,
                            const float* __restrict__ w3, u8* __restrict__ wb3,
                            const float* __restrict__ w4, u8* __restrict__ wb4,
                            float* accs, float* zbuf) {
    int blk = blockIdx.x;
    if (blk == 0) {
        if (threadIdx.x < 8)  accs[threadIdx.x] = 0.f;
        if (threadIdx.x < 64) zbuf[threadIdx.x] = 0.f;
        return;
    }
    const float* w; u8* wb; int CIN, CO, idx;
    if (blk <= 288)       { w = w2; wb = wb2; CIN = 64;  CO = 128; idx = (blk - 1) * 256 + threadIdx.x; }
    else if (blk <= 1440) { w = w3; wb = wb3; CIN = 128; CO = 256; idx = (blk - 289) * 256 + threadIdx.x; }
    else                  { w = w4; wb = wb4; CIN = 256; CO = 256; idx = (blk - 1441) * 256 + threadIdx.x; }
    int n = CO * 9 * CIN;
    if (idx >= n) return;
    int t = idx % 9;
    int rest = idx / 9;
    int ci = rest % CIN;
    int co = rest / CIN;
    float v = w[idx];            // w flat = ((co*CIN+ci)*9 + t)
    int p = ci >> 5, c32 = ci & 31;
    size_t off = (size_t)p * 288 * CO;
    if (t < 8) {
        off += (((size_t)t * 2 + (c32 >> 4)) * CO + co) * 16 + (c32 & 15);
    } else {
        off += 256 * (size_t)CO + (((size_t)(c32 >> 4)) * CO + co) * 16 + (c32 & 15);
    }
    int r = __builtin_amdgcn_cvt_pk_fp8_f32(v, v, 0, false);
    wb[off] = (u8)(r & 0xff);
}

// ---------------------------------------------------------------------------
// loss: blocks [0,1960) = SSIM (b = blk/245), blocks [1960,2472) = MSE (f4)
// ---------------------------------------------------------------------------
__global__ void loss_kernel(const float* __restrict__ x, const float* __restrict__ y,
                            float* __restrict__ accs) {
    const int blk = blockIdx.x;
    float val = 0.f;
    float* dst;
    if (blk < 1960) {
        dst = accs + 1;
        const int b = blk / 245;
        const int t = (blk - b * 245) * 256 + threadIdx.x;
        if (t < 250 * 250) {
            const int i = t / 250, j = t - (t / 250) * 250;
            const float* xp = x + (size_t)b * 65536;
            const float* yp = y + (size_t)b * 65536;
            float sx = 0.f, sy = 0.f, sxx = 0.f, syy = 0.f, sxy = 0.f;
            #pragma unroll
            for (int dy = 0; dy < 7; ++dy) {
                const float* xr = xp + (size_t)(i + dy) * 256 + j;
                const float* yr = yp + (size_t)(i + dy) * 256 + j;
                #pragma unroll
                for (int dx = 0; dx < 7; ++dx) {
                    float a = xr[dx], c = yr[dx];
                    sx += a; sy += c;
                    sxx += a * a; syy += c * c; sxy += a * c;
                }
            }
            const float inv = 1.f / 49.f;
            const float cn  = 49.f / 48.f;
            float ux = sx * inv, uy = sy * inv;
            float vx  = cn * (sxx * inv - ux * ux);
            float vy  = cn * (syy * inv - uy * uy);
            float vxy = cn * (sxy * inv - ux * uy);
            const float C1 = 1e-4f, C2 = 9e-4f;
            val = ((2.f * ux * uy + C1) * (2.f * vxy + C2)) /
                  ((ux * ux + uy * uy + C1) * (vx + vy + C2));
        }
    } else {
        dst = accs + 0;
        int i = (blk - 1960) * 256 + threadIdx.x;   // < 131072 float4s
        float4 a = ((const float4*)x)[i];
        float4 b = ((const float4*)y)[i];
        float d0 = a.x - b.x, d1 = a.y - b.y, d2 = a.z - b.z, d3 = a.w - b.w;
        val = d0 * d0 + d1 * d1 + d2 * d2 + d3 * d3;
    }
    block_reduce_atomic(val, dst);
}

__global__ void finalize_kernel(const float* __restrict__ accs, float* __restrict__ out) {
    if (threadIdx.x == 0) {
        float mse    = accs[0] * (1.f / 524288.f);
        float ssim_l = 1.f - accs[1] * (1.f / 500000.f);
        float perc   = accs[2] * (1.f / 33554432.f);
        out[0] = mse + 0.5f * ssim_l + 0.1f * perc;
        out[1] = mse;
        out[2] = ssim_l;
        out[3] = perc;
    }
}

// ---------------------------------------------------------------------------
// conv1: CIN=1, CO=64, fp32 NCHW in -> fp8 planar NC8HW8 out, relu.
// ---------------------------------------------------------------------------
__global__ __launch_bounds__(256) void conv1_kernel(
    const float* __restrict__ sr, const float* __restrict__ hr, int nb, int b0,
    const float* __restrict__ w, const float* __restrict__ bias,
    u8* __restrict__ out) {
    const int H = 256, W = 256;
    const int img = blockIdx.y;
    const float* in = (img < nb) ? (sr + (size_t)(b0 + img) * 65536)
                                 : (hr + (size_t)(b0 + img - nb) * 65536);
    int px = blockIdx.x * 256 + threadIdx.x;
    int y = px >> 8, x = px & 255;
    float p[9];
    #pragma unroll
    for (int dy = 0; dy < 3; ++dy)
        #pragma unroll
        for (int dx = 0; dx < 3; ++dx) {
            int gy = y + dy - 1, gx = x + dx - 1;
            float v = 0.f;
            if ((unsigned)gy < (unsigned)H && (unsigned)gx < (unsigned)W)
                v = in[(size_t)gy * W + gx];
            p[dy * 3 + dx] = v;
        }
    #pragma unroll
    for (int g = 0; g < 8; ++g) {
        float v[8];
        #pragma unroll
        for (int c = 0; c < 8; ++c) {
            int co = g * 8 + c;
            float a = bias[co];
            #pragma unroll
            for (int k = 0; k < 9; ++k) a += w[co * 9 + k] * p[k];
            v[c] = fmaxf(a, 0.f);
        }
        uint2 o;
        int r;
        r = __builtin_amdgcn_cvt_pk_fp8_f32(v[0], v[1], 0, false);
        o.x = __builtin_amdgcn_cvt_pk_fp8_f32(v[2], v[3], r, true);
        r = __builtin_amdgcn_cvt_pk_fp8_f32(v[4], v[5], 0, false);
        o.y = __builtin_amdgcn_cvt_pk_fp8_f32(v[6], v[7], r, true);
        *(uint2*)(out + (((size_t)img * 8 + g) * 65536 + px) * 8) = o;
    }
}

// ---------------------------------------------------------------------------
// NARROW conv (R12-proven, unchanged): 64co x 16y x 16x, dbuf 2x32KB.
// EPI: 0 = planar fp8 store, 3 = fused perceptual vs planar-fp8 fref.
// ---------------------------------------------------------------------------
#define BUF_SZ   32768
#define N_ACT_CH 720
#define N_CHUNK  1872
#define WT_BOFF  11520     // 720*16

template <int CIN, int EPI>
__global__ __launch_bounds__(256, 2) void conv_mx(
    const u8* __restrict__ in, const u8* __restrict__ wb,
    const float* __restrict__ bias, u8* __restrict__ out,
    int H, int W, int CO,
    const float* __restrict__ zbuf,
    const u8* __restrict__ fref, float* __restrict__ pacc) {
    const int tid  = threadIdx.x;
    const int lane = tid & 63;
    const int wn   = tid >> 6;
    const int xl = lane & 15;
    const int kq = lane >> 4;
    const int x0 = blockIdx.x * 16;
    const int y0 = blockIdx.y * 16;
    const int ngrp = CO >> 6;
    const int img = blockIdx.z / ngrp;
    const int co0 = (blockIdx.z - img * ngrp) << 6;

    __shared__ __align__(16) char smem[2 * BUF_SZ];

    f32x4 acc[4][4];
    #pragma unroll
    for (int m = 0; m < 4; ++m)
        #pragma unroll
        for (int n = 0; n < 4; ++n) acc[m][n] = (f32x4){0.f, 0.f, 0.f, 0.f};

    const size_t HW = (size_t)H * W;
    const u8* inp = in + (size_t)img * (CIN >> 3) * HW * 8;

    const char* srcp[8];
    long adv[8];
    #pragma unroll
    for (int i = 0; i < 8; ++i) {
        int c = tid + i * 256;
        srcp[i] = (const char*)zbuf;
        adv[i] = 0;
        if (c < N_ACT_CH) {
            int g = c / 180, r = c - g * 180;
            int row = r / 10, pp = r - row * 10;
            int gy = y0 - 1 + row, colb = x0 - 2 + pp * 2;
            if ((unsigned)gy < (unsigned)H && (unsigned)colb < (unsigned)(W - 1)) {
                srcp[i] = (const char*)(inp + ((size_t)g * HW + (size_t)gy * W + colb) * 8);
                adv[i] = 4 * HW * 8;
            }
        } else if (c < N_CHUNK) {
            int c2 = c - N_ACT_CH;
            size_t o;
            if (c2 < 1024) {
                int gt = c2 >> 6, co = c2 & 63;
                o = ((size_t)gt * CO + co0 + co) * 16;
            } else {
                int c3 = c2 - 1024;
                int q = c3 >> 6, co = c3 & 63;
                o = 256 * (size_t)CO + ((size_t)q * CO + co0 + co) * 16;
            }
            srcp[i] = (const char*)(wb + o);
            adv[i] = 288 * (size_t)CO;
        }
    }

    int mxo[2];
    #pragma unroll
    for (int g = 0; g < 2; ++g) {
        int t = g * 4 + kq;
        int dy = t / 3, dx = t - dy * 3;
        mxo[g] = (dy * 20 + dx) * 8;
    }
    const int abase = ((wn * 4) * 20 + xl + 1) * 8;
    const int awmx  = WT_BOFF + kq * 2048 + xl * 16;
    const int aw8   = WT_BOFF + 16384 + (kq >> 1) * 1024 + xl * 16 + (kq & 1) * 8;
    const int ab8   = kq * 2880 + abase + (2 * 20 + 2) * 8;

    const int P = CIN / 32;

    {
        char* d = smem + tid * 16;
        #pragma unroll
        for (int i = 0; i < 8; ++i) {
            gload_lds16(srcp[i], d + i * 4096);
            srcp[i] += adv[i];
        }
    }

    for (int p = 0; p < P; ++p) {
        __syncthreads();
        if (p + 1 < P) {
            char* d = smem + ((p + 1) & 1) * BUF_SZ + tid * 16;
            #pragma unroll
            for (int i = 0; i < 8; ++i) {
                gload_lds16(srcp[i], d + i * 4096);
                srcp[i] += adv[i];
            }
        }
        const char* base = smem + (p & 1) * BUF_SZ;
        #pragma unroll
        for (int g = 0; g < 2; ++g) {
            i32x8 A[4];
            #pragma unroll
            for (int mt = 0; mt < 4; ++mt) {
                const char* pa = base + awmx + g * 8192 + mt * 256;
                U2 u{*(const u32x4*)pa, *(const u32x4*)(pa + 1024)};
                A[mt] = __builtin_bit_cast(i32x8, u);
            }
            #pragma unroll
            for (int nt = 0; nt < 4; ++nt) {
                const char* pb = base + abase + mxo[g] + nt * 160;
                L4 l{*(const long*)pb, *(const long*)(pb + 2880),
                     *(const long*)(pb + 5760), *(const long*)(pb + 8640)};
                i32x8 B = __builtin_bit_cast(i32x8, l);
                #pragma unroll
                for (int mt = 0; mt < 4; ++mt)
                    acc[mt][nt] = __builtin_amdgcn_mfma_scale_f32_16x16x128_f8f6f4(
                        A[mt], B, acc[mt][nt], 0, 0,
                        0, 0x7F7F7F7F, 0, 0x7F7F7F7F);
            }
        }
        {
            long A8[4], B8[4];
            #pragma unroll
            for (int mt = 0; mt < 4; ++mt)
                A8[mt] = *(const long*)(base + aw8 + mt * 256);
            #pragma unroll
            for (int nt = 0; nt < 4; ++nt)
                B8[nt] = *(const long*)(base + ab8 + nt * 160);
            #pragma unroll
            for (int mt = 0; mt < 4; ++mt)
                #pragma unroll
                for (int nt = 0; nt < 4; ++nt)
                    acc[mt][nt] = __builtin_amdgcn_mfma_f32_16x16x32_fp8_fp8(
                        A8[mt], B8[nt], acc[mt][nt], 0, 0, 0);
        }
    }

    // C/D: col(px) = xl; row(co within 16) = kq*4 + reg.
    if (EPI == 0) {
        #pragma unroll
        for (int nt = 0; nt < 4; ++nt) {
            const int y = y0 + wn * 4 + nt;
            #pragma unroll
            for (int mt = 0; mt < 4; ++mt) {
                const int cb = co0 + mt * 16 + kq * 4;
                const f32x4 bv = *(const f32x4*)(bias + cb);
                float v[4];
                #pragma unroll
                for (int r = 0; r < 4; ++r) v[r] = fmaxf(acc[mt][nt][r] + bv[r], 0.f);
                int w0 = __builtin_amdgcn_cvt_pk_fp8_f32(v[0], v[1], 0, false);
                w0 = __builtin_amdgcn_cvt_pk_fp8_f32(v[2], v[3], w0, true);
                *(int*)(out + (((size_t)img * (CO >> 3) + (cb >> 3)) * HW +
                               (size_t)y * W + x0 + xl) * 8 + (cb & 7)) = w0;
            }
        }
    } else {
        float s = 0.f;
        #pragma unroll
        for (int nt = 0; nt < 4; ++nt) {
            const int y = y0 + wn * 4 + nt;
            #pragma unroll
            for (int mt = 0; mt < 4; ++mt) {
                const int cb = co0 + mt * 16 + kq * 4;
                const f32x4 bv = *(const f32x4*)(bias + cb);
                int f = *(const int*)(fref + (((size_t)img * (CO >> 3) + (cb >> 3)) * HW +
                                              (size_t)y * W + x0 + xl) * 8 + (cb & 7));
                f32x2 flo = __builtin_amdgcn_cvt_pk_f32_fp8(f, false);
                f32x2 fhi = __builtin_amdgcn_cvt_pk_f32_fp8(f, true);
                float fr[4] = {flo[0], flo[1], fhi[0], fhi[1]};
                #pragma unroll
                for (int r = 0; r < 4; ++r) {
                    float v = fmaxf(acc[mt][nt][r] + bv[r], 0.f);
                    float d = fr[r] - v;
                    s += d * d;
                }
            }
        }
        #pragma unroll
        for (int o = 32; o > 0; o >>= 1) s += __shfl_down(s, o, 64);
        __syncthreads();
        if (lane == 0) *(float*)(smem + wn * 4) = s;
        __syncthreads();
        if (tid == 0) {
            float tot = *(float*)(smem) + *(float*)(smem + 4) +
                        *(float*)(smem + 8) + *(float*)(smem + 12);
            atomicAdd(pacc, tot);
        }
    }
}

// ---------------------------------------------------------------------------
// WIDE conv: 64co x 16y x 32x tile, wave m4n8 (nt: row=nt>>1, xhalf=nt&1),
// SINGLE 39.2 KB buffer (3-4 blocks/CU; cross-block overlap replaces dbuf).
// act: [q:4 planes 5184B][18 rows 288B][18 colpairs 16B]; wt layout as narrow
// at offset 20736. Same MX tap-packed K-loop. EPI: 0 = fp8 store, 1 = +pool.
// ---------------------------------------------------------------------------
#define WBUF_SZ   39168
#define WN_ACT    1296
#define WN_CHUNK  2448
#define WWT_BOFF  20736    // 1296*16

template <int CIN, int EPI>
__global__ __launch_bounds__(256) void conv_mxw(
    const u8* __restrict__ in, const u8* __restrict__ wb,
    const float* __restrict__ bias, u8* __restrict__ out,
    int H, int W, int CO,
    const float* __restrict__ zbuf) {
    const int tid  = threadIdx.x;
    const int lane = tid & 63;
    const int wn   = tid >> 6;
    const int xl = lane & 15;
    const int kq = lane >> 4;
    const int x0 = blockIdx.x * 32;
    const int y0 = blockIdx.y * 16;
    const int ngrp = CO >> 6;
    const int img = blockIdx.z / ngrp;
    const int co0 = (blockIdx.z - img * ngrp) << 6;

    __shared__ __align__(16) char smem[WBUF_SZ];

    f32x4 acc[4][8];
    #pragma unroll
    for (int m = 0; m < 4; ++m)
        #pragma unroll
        for (int n = 0; n < 8; ++n) acc[m][n] = (f32x4){0.f, 0.f, 0.f, 0.f};

    const size_t HW = (size_t)H * W;
    const u8* inp = in + (size_t)img * (CIN >> 3) * HW * 8;
    const long actAdv = 4 * (long)HW * 8;
    const long wtAdv  = 288 * (long)CO;

    // staging chunks: act c<1296: g=c/324, row=(c%324)/18, cp=(c%324)%18
    //                 wt 1296..2448: same map as narrow
    const char* srcp[10];
    unsigned am = 0, wm = 0;     // advance masks
    #pragma unroll
    for (int i = 0; i < 10; ++i) {
        int c = tid + i * 256;
        srcp[i] = (const char*)zbuf;
        if (c < WN_ACT) {
            int g = c / 324, r2 = c - g * 324;
            int row = r2 / 18, cp = r2 - row * 18;
            int gy = y0 - 1 + row, colb = x0 - 2 + cp * 2;
            if ((unsigned)gy < (unsigned)H && (unsigned)colb < (unsigned)(W - 1)) {
                srcp[i] = (const char*)(inp + ((size_t)g * HW + (size_t)gy * W + colb) * 8);
                am |= 1u << i;
            }
        } else if (c < WN_CHUNK) {
            int c2 = c - WN_ACT;
            size_t o;
            if (c2 < 1024) {
                int gt = c2 >> 6, co = c2 & 63;
                o = ((size_t)gt * CO + co0 + co) * 16;
            } else {
                int c3 = c2 - 1024;
                int q = c3 >> 6, co = c3 & 63;
                o = 256 * (size_t)CO + ((size_t)q * CO + co0 + co) * 16;
            }
            srcp[i] = (const char*)(wb + o);
            wm |= 1u << i;
        }
    }
    const bool sl9 = (tid + 2304) < WN_CHUNK;   // last slot partial (tid<144)

    int mxo[2];
    #pragma unroll
    for (int g = 0; g < 2; ++g) {
        int t = g * 4 + kq;
        int dy = t / 3, dx = t - dy * 3;
        mxo[g] = dy * 288 + dx * 8;
    }
    const int abase = (wn * 4) * 288 + (xl + 1) * 8;   // + q*5184 + (nt>>1)*288 + (nt&1)*128
    const int awmx  = WWT_BOFF + kq * 2048 + xl * 16;
    const int aw8   = WWT_BOFF + 16384 + (kq >> 1) * 1024 + xl * 16 + (kq & 1) * 8;
    const int ab8   = kq * 5184 + abase + 2 * 288 + 2 * 8;

    const int P = CIN / 32;

    for (int p = 0; p < P; ++p) {
        if (p) __syncthreads();      // all waves done reading buffer
        {
            char* d = smem + tid * 16;
            #pragma unroll
            for (int i = 0; i < 9; ++i) gload_lds16(srcp[i], d + i * 4096);
            if (sl9) gload_lds16(srcp[9], d + 9 * 4096);
            #pragma unroll
            for (int i = 0; i < 10; ++i) {
                if (am & (1u << i)) srcp[i] += actAdv;
                else if (wm & (1u << i)) srcp[i] += wtAdv;
            }
        }
        __syncthreads();             // drain loads

        #pragma unroll
        for (int g = 0; g < 2; ++g) {
            i32x8 A[4];
            #pragma unroll
            for (int mt = 0; mt < 4; ++mt) {
                const char* pa = smem + awmx + g * 8192 + mt * 256;
                U2 u{*(const u32x4*)pa, *(const u32x4*)(pa + 1024)};
                A[mt] = __builtin_bit_cast(i32x8, u);
            }
            #pragma unroll
            for (int nt = 0; nt < 8; ++nt) {
                const char* pb = smem + abase + mxo[g] + (nt >> 1) * 288 + (nt & 1) * 128;
                L4 l{*(const long*)pb, *(const long*)(pb + 5184),
                     *(const long*)(pb + 10368), *(const long*)(pb + 15552)};
                i32x8 B = __builtin_bit_cast(i32x8, l);
                #pragma unroll
                for (int mt = 0; mt < 4; ++mt)
                    acc[mt][nt] = __builtin_amdgcn_mfma_scale_f32_16x16x128_f8f6f4(
                        A[mt], B, acc[mt][nt], 0, 0,
                        0, 0x7F7F7F7F, 0, 0x7F7F7F7F);
            }
        }
        {
            long A8[4];
            #pragma unroll
            for (int mt = 0; mt < 4; ++mt)
                A8[mt] = *(const long*)(smem + aw8 + mt * 256);
            #pragma unroll
            for (int nt = 0; nt < 8; ++nt) {
                long B8 = *(const long*)(smem + ab8 + (nt >> 1) * 288 + (nt & 1) * 128);
                #pragma unroll
                for (int mt = 0; mt < 4; ++mt)
                    acc[mt][nt] = __builtin_amdgcn_mfma_f32_16x16x32_fp8_fp8(
                        A8[mt], B8, acc[mt][nt], 0, 0, 0);
            }
        }
    }

    // C/D: col(px) = xl; row(co within 16) = kq*4 + reg.
    if (EPI == 0) {
        #pragma unroll
        for (int nt = 0; nt < 8; ++nt) {
            const int y = y0 + wn * 4 + (nt >> 1);
            const int x = x0 + (nt & 1) * 16 + xl;
            #pragma unroll
            for (int mt = 0; mt < 4; ++mt) {
                const int cb = co0 + mt * 16 + kq * 4;
                const f32x4 bv = *(const f32x4*)(bias + cb);
                float v[4];
                #pragma unroll
                for (int r = 0; r < 4; ++r) v[r] = fmaxf(acc[mt][nt][r] + bv[r], 0.f);
                int w0 = __builtin_amdgcn_cvt_pk_fp8_f32(v[0], v[1], 0, false);
                w0 = __builtin_amdgcn_cvt_pk_fp8_f32(v[2], v[3], w0, true);
                *(int*)(out + (((size_t)img * (CO >> 3) + (cb >> 3)) * HW +
                               (size_t)y * W + x) * 8 + (cb & 7)) = w0;
            }
        }
    } else {
        const int Hp = H >> 1, Wp = W >> 1;
        const size_t HWp = (size_t)Hp * Wp;
        #pragma unroll
        for (int j = 0; j < 2; ++j) {
            const int py = (y0 + wn * 4 + 2 * j) >> 1;
            #pragma unroll
            for (int xh = 0; xh < 2; ++xh) {
                const int px = (x0 + xh * 16 + xl) >> 1;
                #pragma unroll
                for (int mt = 0; mt < 4; ++mt) {
                    const int cb = co0 + mt * 16 + kq * 4;
                    const f32x4 bv = *(const f32x4*)(bias + cb);
                    float v[4];
                    #pragma unroll
                    for (int r = 0; r < 4; ++r) {
                        float a = acc[mt][4 * j + xh][r] + bv[r];
                        float b = acc[mt][4 * j + 2 + xh][r] + bv[r];
                        float m = fmaxf(a, b);
                        m = fmaxf(m, __shfl_xor(m, 1));   // fold x pair
                        v[r] = fmaxf(m, 0.f);
                    }
                    if (!(lane & 1)) {
                        int w0 = __builtin_amdgcn_cvt_pk_fp8_f32(v[0], v[1], 0, false);
                        w0 = __builtin_amdgcn_cvt_pk_fp8_f32(v[2], v[3], w0, true);
                        *(int*)(out + (((size_t)img * (CO >> 3) + (cb >> 3)) * HWp +
                                       (size_t)py * Wp + px) * 8 + (cb & 7)) = w0;
                    }
                }
            }
        }
    }
}

// ---------------------------------------------------------------------------
// launch
// ---------------------------------------------------------------------------
extern "C" void kernel_launch(void* const* d_in, const int* in_sizes, int n_in,
                              void* d_out, int out_size, void* d_ws, size_t ws_size,
                              hipStream_t stream) {
    const float* sr = (const float*)d_in[0];
    const float* hr = (const float*)d_in[1];
    const float* w1 = (const float*)d_in[2];
    const float* b1 = (const float*)d_in[3];
    const float* w2 = (const float*)d_in[4];
    const float* b2 = (const float*)d_in[5];
    const float* w3 = (const float*)d_in[6];
    const float* b3 = (const float*)d_in[7];
    const float* w4 = (const float*)d_in[8];
    const float* b4 = (const float*)d_in[9];
    float* out = (float*)d_out;

    char* ws = (char*)d_ws;
    size_t off = 0;
    float* accs = (float*)(ws + off); off += 256;
    float* zbuf = (float*)(ws + off); off += 256;
    u8* wb2 = (u8*)(ws + off); off += (size_t)128 * 9 * 64;
    u8* wb3 = (u8*)(ws + off); off += (size_t)256 * 9 * 128;
    u8* wb4 = (u8*)(ws + off); off += (size_t)256 * 9 * 256;
    const size_t fixed = (off + 255) & ~(size_t)255;

    const size_t MB = 1024u * 1024u;
    // per batch-image pair (sr+hr): A 8MB, P 4MB, F 2MB = 14MB
    int nb = 8;
    while (nb > 1 && fixed + (size_t)nb * 14 * MB > ws_size) nb >>= 1;

    u8* A = (u8*)(ws + fixed);                          // fp8 planar (conv1 out / conv3 out)
    u8* P = (u8*)(ws + fixed + (size_t)nb * 8 * MB);    // fp8 planar pooled
    u8* F = (u8*)(ws + fixed + (size_t)nb * 12 * MB);   // fp8 planar (sr features)

    prep_kernel<<<3745, 256, 0, stream>>>(w2, wb2, w3, wb3, w4, wb4, accs, zbuf);
    loss_kernel<<<2472, 256, 0, stream>>>(sr, hr, accs);

    for (int b0 = 0; b0 < 8; b0 += nb) {
        const int ni = 2 * nb;   // sr images then hr images
        // conv1 (sr+hr merged) -> A
        conv1_kernel<<<dim3(256, ni), 256, 0, stream>>>(sr, hr, nb, b0, w1, b1, A);
        // conv2 + fused pool (merged, WIDE) -> P
        conv_mxw<64, 1><<<dim3(8, 16, ni * 2), 256, 0, stream>>>(
            A, wb2, b2, P, 256, 256, 128, zbuf);
        // conv3 (merged, WIDE) -> A (reuse)
        conv_mxw<128, 0><<<dim3(4, 8, ni * 4), 256, 0, stream>>>(
            P, wb3, b3, A, 128, 128, 256, zbuf);
        // conv4 sr -> F (planar fp8)
        conv_mx<256, 0><<<dim3(8, 8, nb * 4), 256, 0, stream>>>(
            A, wb4, b4, F, 128, 128, 256, zbuf, nullptr, nullptr);
        // conv4 hr, fused perceptual vs F
        conv_mx<256, 3><<<dim3(8, 8, nb * 4), 256, 0, stream>>>(
            A + (size_t)nb * 4 * MB, wb4, b4, nullptr, 128, 128, 256, zbuf, F, accs + 2);
    }

    finalize_kernel<<<1, 1, 0, stream>>>(accs, out);
}

// Round 14
// 433.608 us; speedup vs baseline: 1.1963x; 1.1963x over previous
//
#include <hip/hip_runtime.h>
#include <hip/hip_bf16.h>

typedef __hip_bfloat16 bf16;
typedef unsigned char u8;
typedef __attribute__((ext_vector_type(4))) float f32x4;
typedef __attribute__((ext_vector_type(8))) int i32x8;
typedef __attribute__((ext_vector_type(4))) unsigned int u32x4;

struct L4 { long a, b, c, d; };
struct U2 { u32x4 x, y; };

// async global->LDS 16B copy; LDS dst must be wave-uniform base + lane*16
typedef __attribute__((address_space(3))) unsigned int lds_uint;
typedef __attribute__((address_space(1))) const unsigned int g_uint;
__device__ inline void gload_lds16(const void* g, void* l) {
    __builtin_amdgcn_global_load_lds((g_uint*)g, (lds_uint*)l, 16, 0, 0);
}

__device__ inline void block_reduce_atomic(float v, float* dst) {
    #pragma unroll
    for (int o = 32; o > 0; o >>= 1) v += __shfl_down(v, o, 64);
    __shared__ float ws[8];
    const int lane = threadIdx.x & 63;
    const int wid  = threadIdx.x >> 6;
    if (lane == 0) ws[wid] = v;
    __syncthreads();
    if (threadIdx.x == 0) {
        float s = 0.f;
        const int nw = (blockDim.x + 63) >> 6;
        for (int i = 0; i < nw; ++i) s += ws[i];
        atomicAdd(dst, s);
    }
}

// ---------------------------------------------------------------------------
// prep+loss merged (accs/zbuf zeroed by hipMemsetAsync before this).
// blocks [0,3744): weight repack to MX layout; [3744,6216): ssim + mse.
// wt layout per 32ch phase p: [t0..7][q(16ch)][CO][16B] then tap8 [q][CO][16B]
// ---------------------------------------------------------------------------
__global__ void prep_loss_kernel(
    const float* __restrict__ w2, u8* __restrict__ wb2,
    const float* __restrict__ w3, u8* __restrict__ wb3,
    const float* __restrict__ w4, u8* __restrict__ wb4,
    const float* __restrict__ x, const float* __restrict__ y,
    float* __restrict__ accs) {
    const int blk = blockIdx.x;
    if (blk < 3744) {
        const float* w; u8* wb; int CIN, CO, idx;
        if (blk < 288)       { w = w2; wb = wb2; CIN = 64;  CO = 128; idx = blk * 256 + threadIdx.x; }
        else if (blk < 1440) { w = w3; wb = wb3; CIN = 128; CO = 256; idx = (blk - 288) * 256 + threadIdx.x; }
        else                 { w = w4; wb = wb4; CIN = 256; CO = 256; idx = (blk - 1440) * 256 + threadIdx.x; }
        int n = CO * 9 * CIN;
        if (idx >= n) return;
        int t = idx % 9;
        int rest = idx / 9;
        int ci = rest % CIN;
        int co = rest / CIN;
        float v = w[idx];            // w flat = ((co*CIN+ci)*9 + t)
        int p = ci >> 5, c32 = ci & 31;
        size_t off = (size_t)p * 288 * CO;
        if (t < 8) off += (((size_t)t * 2 + (c32 >> 4)) * CO + co) * 16 + (c32 & 15);
        else       off += 256 * (size_t)CO + (((size_t)(c32 >> 4)) * CO + co) * 16 + (c32 & 15);
        int r = __builtin_amdgcn_cvt_pk_fp8_f32(v, v, 0, false);
        wb[off] = (u8)(r & 0xff);
        return;
    }
    const int lb = blk - 3744;
    float val = 0.f;
    float* dst;
    if (lb < 1960) {
        dst = accs + 1;
        const int b = lb / 245;
        const int t = (lb - b * 245) * 256 + threadIdx.x;
        if (t < 250 * 250) {
            const int i = t / 250, j = t - (t / 250) * 250;
            const float* xp = x + (size_t)b * 65536;
            const float* yp = y + (size_t)b * 65536;
            float sx = 0.f, sy = 0.f, sxx = 0.f, syy = 0.f, sxy = 0.f;
            #pragma unroll
            for (int dy = 0; dy < 7; ++dy) {
                const float* xr = xp + (size_t)(i + dy) * 256 + j;
                const float* yr = yp + (size_t)(i + dy) * 256 + j;
                #pragma unroll
                for (int dx = 0; dx < 7; ++dx) {
                    float a = xr[dx], c = yr[dx];
                    sx += a; sy += c;
                    sxx += a * a; syy += c * c; sxy += a * c;
                }
            }
            const float inv = 1.f / 49.f;
            const float cn  = 49.f / 48.f;
            float ux = sx * inv, uy = sy * inv;
            float vx  = cn * (sxx * inv - ux * ux);
            float vy  = cn * (syy * inv - uy * uy);
            float vxy = cn * (sxy * inv - ux * uy);
            const float C1 = 1e-4f, C2 = 9e-4f;
            val = ((2.f * ux * uy + C1) * (2.f * vxy + C2)) /
                  ((ux * ux + uy * uy + C1) * (vx + vy + C2));
        }
    } else {
        dst = accs + 0;
        int i = (lb - 1960) * 256 + threadIdx.x;   // < 131072 float4s
        float4 a = ((const float4*)x)[i];
        float4 b = ((const float4*)y)[i];
        float d0 = a.x - b.x, d1 = a.y - b.y, d2 = a.z - b.z, d3 = a.w - b.w;
        val = d0 * d0 + d1 * d1 + d2 * d2 + d3 * d3;
    }
    block_reduce_atomic(val, dst);
}

__global__ void finalize_kernel(const float* __restrict__ accs, float* __restrict__ out) {
    if (threadIdx.x == 0) {
        float mse    = accs[0] * (1.f / 524288.f);
        float ssim_l = 1.f - accs[1] * (1.f / 500000.f);
        float perc   = accs[2] * (1.f / 33554432.f);
        out[0] = mse + 0.5f * ssim_l + 0.1f * perc;
        out[1] = mse;
        out[2] = ssim_l;
        out[3] = perc;
    }
}

// ---------------------------------------------------------------------------
// conv1: CIN=1, CO=64, fp32 NCHW in -> fp8 planar NC8HW8 out, relu.
// ---------------------------------------------------------------------------
__global__ __launch_bounds__(256) void conv1_kernel(
    const float* __restrict__ sr, const float* __restrict__ hr, int nb, int b0,
    const float* __restrict__ w, const float* __restrict__ bias,
    u8* __restrict__ out) {
    const int H = 256, W = 256;
    const int img = blockIdx.y;
    const float* in = (img < nb) ? (sr + (size_t)(b0 + img) * 65536)
                                 : (hr + (size_t)(b0 + img - nb) * 65536);
    int px = blockIdx.x * 256 + threadIdx.x;
    int y = px >> 8, x = px & 255;
    float p[9];
    #pragma unroll
    for (int dy = 0; dy < 3; ++dy)
        #pragma unroll
        for (int dx = 0; dx < 3; ++dx) {
            int gy = y + dy - 1, gx = x + dx - 1;
            float v = 0.f;
            if ((unsigned)gy < (unsigned)H && (unsigned)gx < (unsigned)W)
                v = in[(size_t)gy * W + gx];
            p[dy * 3 + dx] = v;
        }
    #pragma unroll
    for (int g = 0; g < 8; ++g) {
        float v[8];
        #pragma unroll
        for (int c = 0; c < 8; ++c) {
            int co = g * 8 + c;
            float a = bias[co];
            #pragma unroll
            for (int k = 0; k < 9; ++k) a += w[co * 9 + k] * p[k];
            v[c] = fmaxf(a, 0.f);
        }
        uint2 o;
        int r;
        r = __builtin_amdgcn_cvt_pk_fp8_f32(v[0], v[1], 0, false);
        o.x = __builtin_amdgcn_cvt_pk_fp8_f32(v[2], v[3], r, true);
        r = __builtin_amdgcn_cvt_pk_fp8_f32(v[4], v[5], 0, false);
        o.y = __builtin_amdgcn_cvt_pk_fp8_f32(v[6], v[7], r, true);
        *(uint2*)(out + (((size_t)img * 8 + g) * 65536 + px) * 8) = o;
    }
}

// ---------------------------------------------------------------------------
// NARROW conv (R12-proven): 64co x 16y x 16x, MX tap-packed K, dbuf 2x32KB.
// EPI: 0 = planar fp8 store, 1 = planar fp8 + fused 2x2 maxpool.
// ---------------------------------------------------------------------------
#define BUF_SZ   32768
#define N_ACT_CH 720
#define N_CHUNK  1872
#define WT_BOFF  11520     // 720*16

template <int CIN, int EPI>
__global__ __launch_bounds__(256, 2) void conv_mx(
    const u8* __restrict__ in, const u8* __restrict__ wb,
    const float* __restrict__ bias, u8* __restrict__ out,
    int H, int W, int CO,
    const float* __restrict__ zbuf) {
    const int tid  = threadIdx.x;
    const int lane = tid & 63;
    const int wn   = tid >> 6;
    const int xl = lane & 15;
    const int kq = lane >> 4;
    const int x0 = blockIdx.x * 16;
    const int y0 = blockIdx.y * 16;
    const int ngrp = CO >> 6;
    const int img = blockIdx.z / ngrp;
    const int co0 = (blockIdx.z - img * ngrp) << 6;

    __shared__ __align__(16) char smem[2 * BUF_SZ];

    f32x4 acc[4][4];
    #pragma unroll
    for (int m = 0; m < 4; ++m)
        #pragma unroll
        for (int n = 0; n < 4; ++n) acc[m][n] = (f32x4){0.f, 0.f, 0.f, 0.f};

    const size_t HW = (size_t)H * W;
    const u8* inp = in + (size_t)img * (CIN >> 3) * HW * 8;

    const char* srcp[8];
    long adv[8];
    #pragma unroll
    for (int i = 0; i < 8; ++i) {
        int c = tid + i * 256;
        srcp[i] = (const char*)zbuf;
        adv[i] = 0;
        if (c < N_ACT_CH) {
            int g = c / 180, r = c - g * 180;
            int row = r / 10, pp = r - row * 10;
            int gy = y0 - 1 + row, colb = x0 - 2 + pp * 2;
            if ((unsigned)gy < (unsigned)H && (unsigned)colb < (unsigned)(W - 1)) {
                srcp[i] = (const char*)(inp + ((size_t)g * HW + (size_t)gy * W + colb) * 8);
                adv[i] = 4 * HW * 8;
            }
        } else if (c < N_CHUNK) {
            int c2 = c - N_ACT_CH;
            size_t o;
            if (c2 < 1024) {
                int gt = c2 >> 6, co = c2 & 63;
                o = ((size_t)gt * CO + co0 + co) * 16;
            } else {
                int c3 = c2 - 1024;
                int q = c3 >> 6, co = c3 & 63;
                o = 256 * (size_t)CO + ((size_t)q * CO + co0 + co) * 16;
            }
            srcp[i] = (const char*)(wb + o);
            adv[i] = 288 * (size_t)CO;
        }
    }

    int mxo[2];
    #pragma unroll
    for (int g = 0; g < 2; ++g) {
        int t = g * 4 + kq;
        int dy = t / 3, dx = t - dy * 3;
        mxo[g] = (dy * 20 + dx) * 8;
    }
    const int abase = ((wn * 4) * 20 + xl + 1) * 8;
    const int awmx  = WT_BOFF + kq * 2048 + xl * 16;
    const int aw8   = WT_BOFF + 16384 + (kq >> 1) * 1024 + xl * 16 + (kq & 1) * 8;
    const int ab8   = kq * 2880 + abase + (2 * 20 + 2) * 8;

    const int P = CIN / 32;

    {
        char* d = smem + tid * 16;
        #pragma unroll
        for (int i = 0; i < 8; ++i) {
            gload_lds16(srcp[i], d + i * 4096);
            srcp[i] += adv[i];
        }
    }

    for (int p = 0; p < P; ++p) {
        __syncthreads();
        if (p + 1 < P) {
            char* d = smem + ((p + 1) & 1) * BUF_SZ + tid * 16;
            #pragma unroll
            for (int i = 0; i < 8; ++i) {
                gload_lds16(srcp[i], d + i * 4096);
                srcp[i] += adv[i];
            }
        }
        const char* base = smem + (p & 1) * BUF_SZ;
        #pragma unroll
        for (int g = 0; g < 2; ++g) {
            i32x8 A[4];
            #pragma unroll
            for (int mt = 0; mt < 4; ++mt) {
                const char* pa = base + awmx + g * 8192 + mt * 256;
                U2 u{*(const u32x4*)pa, *(const u32x4*)(pa + 1024)};
                A[mt] = __builtin_bit_cast(i32x8, u);
            }
            #pragma unroll
            for (int nt = 0; nt < 4; ++nt) {
                const char* pb = base + abase + mxo[g] + nt * 160;
                L4 l{*(const long*)pb, *(const long*)(pb + 2880),
                     *(const long*)(pb + 5760), *(const long*)(pb + 8640)};
                i32x8 B = __builtin_bit_cast(i32x8, l);
                #pragma unroll
                for (int mt = 0; mt < 4; ++mt)
                    acc[mt][nt] = __builtin_amdgcn_mfma_scale_f32_16x16x128_f8f6f4(
                        A[mt], B, acc[mt][nt], 0, 0,
                        0, 0x7F7F7F7F, 0, 0x7F7F7F7F);
            }
        }
        {
            long A8[4], B8[4];
            #pragma unroll
            for (int mt = 0; mt < 4; ++mt)
                A8[mt] = *(const long*)(base + aw8 + mt * 256);
            #pragma unroll
            for (int nt = 0; nt < 4; ++nt)
                B8[nt] = *(const long*)(base + ab8 + nt * 160);
            #pragma unroll
            for (int mt = 0; mt < 4; ++mt)
                #pragma unroll
                for (int nt = 0; nt < 4; ++nt)
                    acc[mt][nt] = __builtin_amdgcn_mfma_f32_16x16x32_fp8_fp8(
                        A8[mt], B8[nt], acc[mt][nt], 0, 0, 0);
        }
    }

    // C/D: col(px) = xl; row(co within 16) = kq*4 + reg.
    if (EPI == 0) {
        #pragma unroll
        for (int nt = 0; nt < 4; ++nt) {
            const int y = y0 + wn * 4 + nt;
            #pragma unroll
            for (int mt = 0; mt < 4; ++mt) {
                const int cb = co0 + mt * 16 + kq * 4;
                const f32x4 bv = *(const f32x4*)(bias + cb);
                float v[4];
                #pragma unroll
                for (int r = 0; r < 4; ++r) v[r] = fmaxf(acc[mt][nt][r] + bv[r], 0.f);
                int w0 = __builtin_amdgcn_cvt_pk_fp8_f32(v[0], v[1], 0, false);
                w0 = __builtin_amdgcn_cvt_pk_fp8_f32(v[2], v[3], w0, true);
                *(int*)(out + (((size_t)img * (CO >> 3) + (cb >> 3)) * HW +
                               (size_t)y * W + x0 + xl) * 8 + (cb & 7)) = w0;
            }
        }
    } else {
        const int Hp = H >> 1, Wp = W >> 1;
        const size_t HWp = (size_t)Hp * Wp;
        #pragma unroll
        for (int j = 0; j < 2; ++j) {
            const int py = (y0 + wn * 4 + 2 * j) >> 1;
            const int px = (x0 + xl) >> 1;
            #pragma unroll
            for (int mt = 0; mt < 4; ++mt) {
                const int cb = co0 + mt * 16 + kq * 4;
                const f32x4 bv = *(const f32x4*)(bias + cb);
                float v[4];
                #pragma unroll
                for (int r = 0; r < 4; ++r) {
                    float a = acc[mt][2 * j][r] + bv[r];
                    float b = acc[mt][2 * j + 1][r] + bv[r];
                    float m = fmaxf(a, b);
                    m = fmaxf(m, __shfl_xor(m, 1));   // fold x pair
                    v[r] = fmaxf(m, 0.f);
                }
                if (!(lane & 1)) {
                    int w0 = __builtin_amdgcn_cvt_pk_fp8_f32(v[0], v[1], 0, false);
                    w0 = __builtin_amdgcn_cvt_pk_fp8_f32(v[2], v[3], w0, true);
                    *(int*)(out + (((size_t)img * (CO >> 3) + (cb >> 3)) * HWp +
                                   (size_t)py * Wp + px) * 8 + (cb & 7)) = w0;
                }
            }
        }
    }
}

// ---------------------------------------------------------------------------
// conv4 DUAL: one block computes the SAME tile for sr (imgs 0..nb-1) and hr
// (imgs nb..2nb-1) in 16 dbuf phases (8 sr + 8 hr). At the pass boundary the
// staging pointers get a uniform fixup (act: +hrFix, since 8 phases advance
// exactly one image; wt: -8*73728) and acc is banked to sacc = relu(acc+b).
// Epilogue: perceptual partial sum((sacc - relu(acc_hr+b))^2) -> atomicAdd.
// F never materialized. CIN=256, CO=256, H=W=128 hardcoded.
// ---------------------------------------------------------------------------
__global__ __launch_bounds__(256, 2) void conv4_dual(
    const u8* __restrict__ in,       // planar fp8, sr imgs then hr imgs
    const u8* __restrict__ wb,
    const float* __restrict__ bias,
    const float* __restrict__ zbuf,
    long hrFix,                      // (nb-1) * 4194304
    float* __restrict__ pacc) {
    const int H = 128, W = 128, CO = 256;
    const size_t HW = 16384;
    const int tid  = threadIdx.x;
    const int lane = tid & 63;
    const int wn   = tid >> 6;
    const int xl = lane & 15;
    const int kq = lane >> 4;
    const int x0 = blockIdx.x * 16;
    const int y0 = blockIdx.y * 16;
    const int img = blockIdx.z >> 2;
    const int co0 = (blockIdx.z & 3) << 6;

    __shared__ __align__(16) char smem[2 * BUF_SZ];

    f32x4 acc[4][4], sacc[4][4];
    #pragma unroll
    for (int m = 0; m < 4; ++m)
        #pragma unroll
        for (int n = 0; n < 4; ++n) acc[m][n] = (f32x4){0.f, 0.f, 0.f, 0.f};

    const u8* inp = in + (size_t)img * 4194304;   // 32 planes * HW * 8

    const char* srcp[8];
    long adv[8];
    #pragma unroll
    for (int i = 0; i < 8; ++i) {
        int c = tid + i * 256;
        srcp[i] = (const char*)zbuf;
        adv[i] = 0;
        if (c < N_ACT_CH) {
            int g = c / 180, r = c - g * 180;
            int row = r / 10, pp = r - row * 10;
            int gy = y0 - 1 + row, colb = x0 - 2 + pp * 2;
            if ((unsigned)gy < (unsigned)H && (unsigned)colb < (unsigned)(W - 1)) {
                srcp[i] = (const char*)(inp + ((size_t)g * HW + (size_t)gy * W + colb) * 8);
                adv[i] = 4 * HW * 8;              // 524288
            }
        } else if (c < N_CHUNK) {
            int c2 = c - N_ACT_CH;
            size_t o;
            if (c2 < 1024) {
                int gt = c2 >> 6, co = c2 & 63;
                o = ((size_t)gt * CO + co0 + co) * 16;
            } else {
                int c3 = c2 - 1024;
                int q = c3 >> 6, co = c3 & 63;
                o = 256 * (size_t)CO + ((size_t)q * CO + co0 + co) * 16;
            }
            srcp[i] = (const char*)(wb + o);
            adv[i] = 288 * (size_t)CO;            // 73728
        }
    }

    int mxo[2];
    #pragma unroll
    for (int g = 0; g < 2; ++g) {
        int t = g * 4 + kq;
        int dy = t / 3, dx = t - dy * 3;
        mxo[g] = (dy * 20 + dx) * 8;
    }
    const int abase = ((wn * 4) * 20 + xl + 1) * 8;
    const int awmx  = WT_BOFF + kq * 2048 + xl * 16;
    const int aw8   = WT_BOFF + 16384 + (kq >> 1) * 1024 + xl * 16 + (kq & 1) * 8;
    const int ab8   = kq * 2880 + abase + (2 * 20 + 2) * 8;

    {
        char* d = smem + tid * 16;
        #pragma unroll
        for (int i = 0; i < 8; ++i) {
            gload_lds16(srcp[i], d + i * 4096);
            srcp[i] += adv[i];
        }
    }

    for (int pp = 0; pp < 16; ++pp) {
        __syncthreads();
        if (pp + 1 < 16) {
            if (pp + 1 == 8) {                    // pass boundary fixup
                #pragma unroll
                for (int i = 0; i < 8; ++i) {
                    if (adv[i] == 524288) srcp[i] += hrFix;
                    else if (adv[i])      srcp[i] -= 8 * 73728;
                }
            }
            char* d = smem + ((pp + 1) & 1) * BUF_SZ + tid * 16;
            #pragma unroll
            for (int i = 0; i < 8; ++i) {
                gload_lds16(srcp[i], d + i * 4096);
                srcp[i] += adv[i];
            }
        }
        const char* base = smem + (pp & 1) * BUF_SZ;
        #pragma unroll
        for (int g = 0; g < 2; ++g) {
            i32x8 A[4];
            #pragma unroll
            for (int mt = 0; mt < 4; ++mt) {
                const char* pa = base + awmx + g * 8192 + mt * 256;
                U2 u{*(const u32x4*)pa, *(const u32x4*)(pa + 1024)};
                A[mt] = __builtin_bit_cast(i32x8, u);
            }
            #pragma unroll
            for (int nt = 0; nt < 4; ++nt) {
                const char* pb = base + abase + mxo[g] + nt * 160;
                L4 l{*(const long*)pb, *(const long*)(pb + 2880),
                     *(const long*)(pb + 5760), *(const long*)(pb + 8640)};
                i32x8 B = __builtin_bit_cast(i32x8, l);
                #pragma unroll
                for (int mt = 0; mt < 4; ++mt)
                    acc[mt][nt] = __builtin_amdgcn_mfma_scale_f32_16x16x128_f8f6f4(
                        A[mt], B, acc[mt][nt], 0, 0,
                        0, 0x7F7F7F7F, 0, 0x7F7F7F7F);
            }
        }
        {
            long A8[4], B8[4];
            #pragma unroll
            for (int mt = 0; mt < 4; ++mt)
                A8[mt] = *(const long*)(base + aw8 + mt * 256);
            #pragma unroll
            for (int nt = 0; nt < 4; ++nt)
                B8[nt] = *(const long*)(base + ab8 + nt * 160);
            #pragma unroll
            for (int mt = 0; mt < 4; ++mt)
                #pragma unroll
                for (int nt = 0; nt < 4; ++nt)
                    acc[mt][nt] = __builtin_amdgcn_mfma_f32_16x16x32_fp8_fp8(
                        A8[mt], B8[nt], acc[mt][nt], 0, 0, 0);
        }
        if (pp == 7) {                             // bank sr features
            #pragma unroll
            for (int mt = 0; mt < 4; ++mt) {
                const int cb = co0 + mt * 16 + kq * 4;
                const f32x4 bv = *(const f32x4*)(bias + cb);
                #pragma unroll
                for (int nt = 0; nt < 4; ++nt) {
                    #pragma unroll
                    for (int r = 0; r < 4; ++r) {
                        sacc[mt][nt][r] = fmaxf(acc[mt][nt][r] + bv[r], 0.f);
                        acc[mt][nt][r] = 0.f;
                    }
                }
            }
        }
    }

    // perceptual partial
    float s = 0.f;
    #pragma unroll
    for (int mt = 0; mt < 4; ++mt) {
        const int cb = co0 + mt * 16 + kq * 4;
        const f32x4 bv = *(const f32x4*)(bias + cb);
        #pragma unroll
        for (int nt = 0; nt < 4; ++nt) {
            #pragma unroll
            for (int r = 0; r < 4; ++r) {
                float v = fmaxf(acc[mt][nt][r] + bv[r], 0.f);
                float d = sacc[mt][nt][r] - v;
                s += d * d;
            }
        }
    }
    #pragma unroll
    for (int o = 32; o > 0; o >>= 1) s += __shfl_down(s, o, 64);
    __syncthreads();
    if (lane == 0) *(float*)(smem + wn * 4) = s;
    __syncthreads();
    if (tid == 0) {
        float tot = *(float*)(smem) + *(float*)(smem + 4) +
                    *(float*)(smem + 8) + *(float*)(smem + 12);
        atomicAdd(pacc, tot);
    }
}

// ---------------------------------------------------------------------------
// launch
// ---------------------------------------------------------------------------
extern "C" void kernel_launch(void* const* d_in, const int* in_sizes, int n_in,
                              void* d_out, int out_size, void* d_ws, size_t ws_size,
                              hipStream_t stream) {
    const float* sr = (const float*)d_in[0];
    const float* hr = (const float*)d_in[1];
    const float* w1 = (const float*)d_in[2];
    const float* b1 = (const float*)d_in[3];
    const float* w2 = (const float*)d_in[4];
    const float* b2 = (const float*)d_in[5];
    const float* w3 = (const float*)d_in[6];
    const float* b3 = (const float*)d_in[7];
    const float* w4 = (const float*)d_in[8];
    const float* b4 = (const float*)d_in[9];
    float* out = (float*)d_out;

    char* ws = (char*)d_ws;
    size_t off = 0;
    float* accs = (float*)(ws + off); off += 256;
    float* zbuf = (float*)(ws + off); off += 256;
    u8* wb2 = (u8*)(ws + off); off += (size_t)128 * 9 * 64;
    u8* wb3 = (u8*)(ws + off); off += (size_t)256 * 9 * 128;
    u8* wb4 = (u8*)(ws + off); off += (size_t)256 * 9 * 256;
    const size_t fixed = (off + 255) & ~(size_t)255;

    const size_t MB = 1024u * 1024u;
    // per batch-image pair (sr+hr): A 8MB, P 4MB = 12MB
    int nb = 8;
    while (nb > 1 && fixed + (size_t)nb * 12 * MB > ws_size) nb >>= 1;

    u8* A = (u8*)(ws + fixed);                          // fp8 planar (conv1 out / conv3 out)
    u8* P = (u8*)(ws + fixed + (size_t)nb * 8 * MB);    // fp8 planar pooled

    hipMemsetAsync(ws, 0, 512, stream);                 // accs + zbuf
    prep_loss_kernel<<<6216, 256, 0, stream>>>(w2, wb2, w3, wb3, w4, wb4, sr, hr, accs);

    for (int b0 = 0; b0 < 8; b0 += nb) {
        const int ni = 2 * nb;   // sr images then hr images
        // conv1 (sr+hr merged) -> A
        conv1_kernel<<<dim3(256, ni), 256, 0, stream>>>(sr, hr, nb, b0, w1, b1, A);
        // conv2 + fused pool (merged) -> P
        conv_mx<64, 1><<<dim3(16, 16, ni * 2), 256, 0, stream>>>(
            A, wb2, b2, P, 256, 256, 128, zbuf);
        // conv3 (merged) -> A (reuse)
        conv_mx<128, 0><<<dim3(8, 8, ni * 4), 256, 0, stream>>>(
            P, wb3, b3, A, 128, 128, 256, zbuf);
        // conv4 dual-pass: sr + hr + fused perceptual, F never materialized
        conv4_dual<<<dim3(8, 8, nb * 4), 256, 0, stream>>>(
            A, wb4, b4, zbuf, (long)(nb - 1) * 4194304, accs + 2);
    }

    finalize_kernel<<<1, 1, 0, stream>>>(accs, out);
}

// Round 15
// 426.256 us; speedup vs baseline: 1.2169x; 1.0172x over previous
//
#include <hip/hip_runtime.h>
#include <hip/hip_bf16.h>

typedef __hip_bfloat16 bf16;
typedef unsigned char u8;
typedef __attribute__((ext_vector_type(4))) float f32x4;
typedef __attribute__((ext_vector_type(8))) int i32x8;
typedef __attribute__((ext_vector_type(4))) unsigned int u32x4;

struct L4 { long a, b, c, d; };
struct U2 { u32x4 x, y; };

// async global->LDS 16B copy; LDS dst must be wave-uniform base + lane*16
typedef __attribute__((address_space(3))) unsigned int lds_uint;
typedef __attribute__((address_space(1))) const unsigned int g_uint;
__device__ inline void gload_lds16(const void* g, void* l) {
    __builtin_amdgcn_global_load_lds((g_uint*)g, (lds_uint*)l, 16, 0, 0);
}

__device__ inline void block_reduce_atomic(float v, float* dst) {
    #pragma unroll
    for (int o = 32; o > 0; o >>= 1) v += __shfl_down(v, o, 64);
    __shared__ float ws[8];
    const int lane = threadIdx.x & 63;
    const int wid  = threadIdx.x >> 6;
    if (lane == 0) ws[wid] = v;
    __syncthreads();
    if (threadIdx.x == 0) {
        float s = 0.f;
        const int nw = (blockDim.x + 63) >> 6;
        for (int i = 0; i < nw; ++i) s += ws[i];
        atomicAdd(dst, s);
    }
}

// ---------------------------------------------------------------------------
// prep+loss merged (accs/zbuf zeroed by hipMemsetAsync before this).
// blocks [0,3744): weight repack to MX layout; [3744,6216): ssim + mse.
// wt layout per 32ch phase p: [t0..7][q(16ch)][CO][16B] then tap8 [q][CO][16B]
// ---------------------------------------------------------------------------
__global__ void prep_loss_kernel(
    const float* __restrict__ w2, u8* __restrict__ wb2,
    const float* __restrict__ w3, u8* __restrict__ wb3,
    const float* __restrict__ w4, u8* __restrict__ wb4,
    const float* __restrict__ x, const float* __restrict__ y,
    float* __restrict__ accs) {
    const int blk = blockIdx.x;
    if (blk < 3744) {
        const float* w; u8* wb; int CIN, CO, idx;
        if (blk < 288)       { w = w2; wb = wb2; CIN = 64;  CO = 128; idx = blk * 256 + threadIdx.x; }
        else if (blk < 1440) { w = w3; wb = wb3; CIN = 128; CO = 256; idx = (blk - 288) * 256 + threadIdx.x; }
        else                 { w = w4; wb = wb4; CIN = 256; CO = 256; idx = (blk - 1440) * 256 + threadIdx.x; }
        int n = CO * 9 * CIN;
        if (idx >= n) return;
        int t = idx % 9;
        int rest = idx / 9;
        int ci = rest % CIN;
        int co = rest / CIN;
        float v = w[idx];            // w flat = ((co*CIN+ci)*9 + t)
        int p = ci >> 5, c32 = ci & 31;
        size_t off = (size_t)p * 288 * CO;
        if (t < 8) off += (((size_t)t * 2 + (c32 >> 4)) * CO + co) * 16 + (c32 & 15);
        else       off += 256 * (size_t)CO + (((size_t)(c32 >> 4)) * CO + co) * 16 + (c32 & 15);
        int r = __builtin_amdgcn_cvt_pk_fp8_f32(v, v, 0, false);
        wb[off] = (u8)(r & 0xff);
        return;
    }
    const int lb = blk - 3744;
    float val = 0.f;
    float* dst;
    if (lb < 1960) {
        dst = accs + 1;
        const int b = lb / 245;
        const int t = (lb - b * 245) * 256 + threadIdx.x;
        if (t < 250 * 250) {
            const int i = t / 250, j = t - (t / 250) * 250;
            const float* xp = x + (size_t)b * 65536;
            const float* yp = y + (size_t)b * 65536;
            float sx = 0.f, sy = 0.f, sxx = 0.f, syy = 0.f, sxy = 0.f;
            #pragma unroll
            for (int dy = 0; dy < 7; ++dy) {
                const float* xr = xp + (size_t)(i + dy) * 256 + j;
                const float* yr = yp + (size_t)(i + dy) * 256 + j;
                #pragma unroll
                for (int dx = 0; dx < 7; ++dx) {
                    float a = xr[dx], c = yr[dx];
                    sx += a; sy += c;
                    sxx += a * a; syy += c * c; sxy += a * c;
                }
            }
            const float inv = 1.f / 49.f;
            const float cn  = 49.f / 48.f;
            float ux = sx * inv, uy = sy * inv;
            float vx  = cn * (sxx * inv - ux * ux);
            float vy  = cn * (syy * inv - uy * uy);
            float vxy = cn * (sxy * inv - ux * uy);
            const float C1 = 1e-4f, C2 = 9e-4f;
            val = ((2.f * ux * uy + C1) * (2.f * vxy + C2)) /
                  ((ux * ux + uy * uy + C1) * (vx + vy + C2));
        }
    } else {
        dst = accs + 0;
        int i = (lb - 1960) * 256 + threadIdx.x;   // < 131072 float4s
        float4 a = ((const float4*)x)[i];
        float4 b = ((const float4*)y)[i];
        float d0 = a.x - b.x, d1 = a.y - b.y, d2 = a.z - b.z, d3 = a.w - b.w;
        val = d0 * d0 + d1 * d1 + d2 * d2 + d3 * d3;
    }
    block_reduce_atomic(val, dst);
}

__global__ void finalize_kernel(const float* __restrict__ accs, float* __restrict__ out) {
    if (threadIdx.x == 0) {
        float mse    = accs[0] * (1.f / 524288.f);
        float ssim_l = 1.f - accs[1] * (1.f / 500000.f);
        float perc   = accs[2] * (1.f / 33554432.f);
        out[0] = mse + 0.5f * ssim_l + 0.1f * perc;
        out[1] = mse;
        out[2] = ssim_l;
        out[3] = perc;
    }
}

// ---------------------------------------------------------------------------
// conv1: CIN=1, CO=64, fp32 NCHW in -> fp8 planar NC8HW8 out, relu.
// ---------------------------------------------------------------------------
__global__ __launch_bounds__(256) void conv1_kernel(
    const float* __restrict__ sr, const float* __restrict__ hr, int nb, int b0,
    const float* __restrict__ w, const float* __restrict__ bias,
    u8* __restrict__ out) {
    const int H = 256, W = 256;
    const int img = blockIdx.y;
    const float* in = (img < nb) ? (sr + (size_t)(b0 + img) * 65536)
                                 : (hr + (size_t)(b0 + img - nb) * 65536);
    int px = blockIdx.x * 256 + threadIdx.x;
    int y = px >> 8, x = px & 255;
    float p[9];
    #pragma unroll
    for (int dy = 0; dy < 3; ++dy)
        #pragma unroll
        for (int dx = 0; dx < 3; ++dx) {
            int gy = y + dy - 1, gx = x + dx - 1;
            float v = 0.f;
            if ((unsigned)gy < (unsigned)H && (unsigned)gx < (unsigned)W)
                v = in[(size_t)gy * W + gx];
            p[dy * 3 + dx] = v;
        }
    #pragma unroll
    for (int g = 0; g < 8; ++g) {
        float v[8];
        #pragma unroll
        for (int c = 0; c < 8; ++c) {
            int co = g * 8 + c;
            float a = bias[co];
            #pragma unroll
            for (int k = 0; k < 9; ++k) a += w[co * 9 + k] * p[k];
            v[c] = fmaxf(a, 0.f);
        }
        uint2 o;
        int r;
        r = __builtin_amdgcn_cvt_pk_fp8_f32(v[0], v[1], 0, false);
        o.x = __builtin_amdgcn_cvt_pk_fp8_f32(v[2], v[3], r, true);
        r = __builtin_amdgcn_cvt_pk_fp8_f32(v[4], v[5], 0, false);
        o.y = __builtin_amdgcn_cvt_pk_fp8_f32(v[6], v[7], r, true);
        *(uint2*)(out + (((size_t)img * 8 + g) * 65536 + px) * 8) = o;
    }
}

#define BUF_SZ   32768
#define N_ACT_CH 720
#define N_CHUNK  1872
#define WT_BOFF  11520     // 720*16

// ---------------------------------------------------------------------------
// conv2 SINGLE-STAGE: CIN=64, CO=128, H=W=256, fused 2x2 maxpool.
// Entire working set (act 64ch: 2x11520 + wt both phases: 2x18432 = 59904 B)
// staged ONCE via 15 gload slots; ONE barrier; both 32-ch phases computed
// back-to-back with zero further syncs. Phase p buffer at smem + p*29952
// (chunk map per phase identical to conv_mx). 2 blocks/CU (119.8 <= 160 KB).
// ---------------------------------------------------------------------------
__global__ __launch_bounds__(256, 2) void conv2_ss(
    const u8* __restrict__ in, const u8* __restrict__ wb,
    const float* __restrict__ bias, u8* __restrict__ out,
    const float* __restrict__ zbuf) {
    const int H = 256, W = 256, CO = 128;
    const size_t HW = 65536;
    const int tid  = threadIdx.x;
    const int lane = tid & 63;
    const int wn   = tid >> 6;
    const int xl = lane & 15;
    const int kq = lane >> 4;
    const int x0 = blockIdx.x * 16;
    const int y0 = blockIdx.y * 16;
    const int img = blockIdx.z >> 1;
    const int co0 = (blockIdx.z & 1) << 6;

    __shared__ __align__(16) char smem[59904];

    f32x4 acc[4][4];
    #pragma unroll
    for (int m = 0; m < 4; ++m)
        #pragma unroll
        for (int n = 0; n < 4; ++n) acc[m][n] = (f32x4){0.f, 0.f, 0.f, 0.f};

    const u8* inp = in + (size_t)img * 8 * HW * 8;   // 8 planes

    // ---- stage all 3744 chunks once (15 slots; slot14 partial tid<160) ----
    {
        char* d = smem + tid * 16;
        #pragma unroll
        for (int i = 0; i < 15; ++i) {
            int c = tid + i * 256;
            if (c >= 2 * N_CHUNK) break;
            int ph = (c >= N_CHUNK) ? 1 : 0;
            int c2 = c - ph * N_CHUNK;
            const char* src = (const char*)zbuf;
            if (c2 < N_ACT_CH) {
                int g = c2 / 180, r = c2 - g * 180;
                int row = r / 10, pp = r - row * 10;
                int gy = y0 - 1 + row, colb = x0 - 2 + pp * 2;
                if ((unsigned)gy < (unsigned)H && (unsigned)colb < (unsigned)(W - 1))
                    src = (const char*)(inp + (((size_t)(g + ph * 4)) * HW +
                                              (size_t)gy * W + colb) * 8);
            } else {
                int c3 = c2 - N_ACT_CH;
                size_t o;
                if (c3 < 1024) {
                    int gt = c3 >> 6, co = c3 & 63;
                    o = ((size_t)gt * CO + co0 + co) * 16;
                } else {
                    int c4 = c3 - 1024;
                    int q = c4 >> 6, co = c4 & 63;
                    o = 256 * (size_t)CO + ((size_t)q * CO + co0 + co) * 16;
                }
                src = (const char*)(wb + (size_t)ph * 288 * CO + o);
            }
            gload_lds16(src, d + i * 4096);
        }
    }

    int mxo[2];
    #pragma unroll
    for (int g = 0; g < 2; ++g) {
        int t = g * 4 + kq;
        int dy = t / 3, dx = t - dy * 3;
        mxo[g] = (dy * 20 + dx) * 8;
    }
    const int abase = ((wn * 4) * 20 + xl + 1) * 8;
    const int awmx  = WT_BOFF + kq * 2048 + xl * 16;
    const int aw8   = WT_BOFF + 16384 + (kq >> 1) * 1024 + xl * 16 + (kq & 1) * 8;
    const int ab8   = kq * 2880 + abase + (2 * 20 + 2) * 8;

    __syncthreads();   // single drain

    #pragma unroll
    for (int p = 0; p < 2; ++p) {
        const char* base = smem + p * 29952;
        #pragma unroll
        for (int g = 0; g < 2; ++g) {
            i32x8 A[4];
            #pragma unroll
            for (int mt = 0; mt < 4; ++mt) {
                const char* pa = base + awmx + g * 8192 + mt * 256;
                U2 u{*(const u32x4*)pa, *(const u32x4*)(pa + 1024)};
                A[mt] = __builtin_bit_cast(i32x8, u);
            }
            #pragma unroll
            for (int nt = 0; nt < 4; ++nt) {
                const char* pb = base + abase + mxo[g] + nt * 160;
                L4 l{*(const long*)pb, *(const long*)(pb + 2880),
                     *(const long*)(pb + 5760), *(const long*)(pb + 8640)};
                i32x8 B = __builtin_bit_cast(i32x8, l);
                #pragma unroll
                for (int mt = 0; mt < 4; ++mt)
                    acc[mt][nt] = __builtin_amdgcn_mfma_scale_f32_16x16x128_f8f6f4(
                        A[mt], B, acc[mt][nt], 0, 0,
                        0, 0x7F7F7F7F, 0, 0x7F7F7F7F);
            }
        }
        {
            long A8[4], B8[4];
            #pragma unroll
            for (int mt = 0; mt < 4; ++mt)
                A8[mt] = *(const long*)(base + aw8 + mt * 256);
            #pragma unroll
            for (int nt = 0; nt < 4; ++nt)
                B8[nt] = *(const long*)(base + ab8 + nt * 160);
            #pragma unroll
            for (int mt = 0; mt < 4; ++mt)
                #pragma unroll
                for (int nt = 0; nt < 4; ++nt)
                    acc[mt][nt] = __builtin_amdgcn_mfma_f32_16x16x32_fp8_fp8(
                        A8[mt], B8[nt], acc[mt][nt], 0, 0, 0);
        }
    }

    // pool epilogue (C/D: col=xl; row(co in 16) = kq*4+reg)
    const int Hp = H >> 1, Wp = W >> 1;
    const size_t HWp = (size_t)Hp * Wp;
    #pragma unroll
    for (int j = 0; j < 2; ++j) {
        const int py = (y0 + wn * 4 + 2 * j) >> 1;
        const int px = (x0 + xl) >> 1;
        #pragma unroll
        for (int mt = 0; mt < 4; ++mt) {
            const int cb = co0 + mt * 16 + kq * 4;
            const f32x4 bv = *(const f32x4*)(bias + cb);
            float v[4];
            #pragma unroll
            for (int r = 0; r < 4; ++r) {
                float a = acc[mt][2 * j][r] + bv[r];
                float b = acc[mt][2 * j + 1][r] + bv[r];
                float m = fmaxf(a, b);
                m = fmaxf(m, __shfl_xor(m, 1));   // fold x pair
                v[r] = fmaxf(m, 0.f);
            }
            if (!(lane & 1)) {
                int w0 = __builtin_amdgcn_cvt_pk_fp8_f32(v[0], v[1], 0, false);
                w0 = __builtin_amdgcn_cvt_pk_fp8_f32(v[2], v[3], w0, true);
                *(int*)(out + (((size_t)img * (CO >> 3) + (cb >> 3)) * HWp +
                               (size_t)py * Wp + px) * 8 + (cb & 7)) = w0;
            }
        }
    }
}

// ---------------------------------------------------------------------------
// NARROW conv (R12-proven): 64co x 16y x 16x, MX tap-packed K, dbuf 2x32KB.
// EPI: 0 = planar fp8 store. (conv3 only now)
// ---------------------------------------------------------------------------
template <int CIN, int EPI>
__global__ __launch_bounds__(256, 2) void conv_mx(
    const u8* __restrict__ in, const u8* __restrict__ wb,
    const float* __restrict__ bias, u8* __restrict__ out,
    int H, int W, int CO,
    const float* __restrict__ zbuf) {
    const int tid  = threadIdx.x;
    const int lane = tid & 63;
    const int wn   = tid >> 6;
    const int xl = lane & 15;
    const int kq = lane >> 4;
    const int x0 = blockIdx.x * 16;
    const int y0 = blockIdx.y * 16;
    const int ngrp = CO >> 6;
    const int img = blockIdx.z / ngrp;
    const int co0 = (blockIdx.z - img * ngrp) << 6;

    __shared__ __align__(16) char smem[2 * BUF_SZ];

    f32x4 acc[4][4];
    #pragma unroll
    for (int m = 0; m < 4; ++m)
        #pragma unroll
        for (int n = 0; n < 4; ++n) acc[m][n] = (f32x4){0.f, 0.f, 0.f, 0.f};

    const size_t HW = (size_t)H * W;
    const u8* inp = in + (size_t)img * (CIN >> 3) * HW * 8;

    const char* srcp[8];
    long adv[8];
    #pragma unroll
    for (int i = 0; i < 8; ++i) {
        int c = tid + i * 256;
        srcp[i] = (const char*)zbuf;
        adv[i] = 0;
        if (c < N_ACT_CH) {
            int g = c / 180, r = c - g * 180;
            int row = r / 10, pp = r - row * 10;
            int gy = y0 - 1 + row, colb = x0 - 2 + pp * 2;
            if ((unsigned)gy < (unsigned)H && (unsigned)colb < (unsigned)(W - 1)) {
                srcp[i] = (const char*)(inp + ((size_t)g * HW + (size_t)gy * W + colb) * 8);
                adv[i] = 4 * HW * 8;
            }
        } else if (c < N_CHUNK) {
            int c2 = c - N_ACT_CH;
            size_t o;
            if (c2 < 1024) {
                int gt = c2 >> 6, co = c2 & 63;
                o = ((size_t)gt * CO + co0 + co) * 16;
            } else {
                int c3 = c2 - 1024;
                int q = c3 >> 6, co = c3 & 63;
                o = 256 * (size_t)CO + ((size_t)q * CO + co0 + co) * 16;
            }
            srcp[i] = (const char*)(wb + o);
            adv[i] = 288 * (size_t)CO;
        }
    }

    int mxo[2];
    #pragma unroll
    for (int g = 0; g < 2; ++g) {
        int t = g * 4 + kq;
        int dy = t / 3, dx = t - dy * 3;
        mxo[g] = (dy * 20 + dx) * 8;
    }
    const int abase = ((wn * 4) * 20 + xl + 1) * 8;
    const int awmx  = WT_BOFF + kq * 2048 + xl * 16;
    const int aw8   = WT_BOFF + 16384 + (kq >> 1) * 1024 + xl * 16 + (kq & 1) * 8;
    const int ab8   = kq * 2880 + abase + (2 * 20 + 2) * 8;

    const int P = CIN / 32;

    {
        char* d = smem + tid * 16;
        #pragma unroll
        for (int i = 0; i < 8; ++i) {
            gload_lds16(srcp[i], d + i * 4096);
            srcp[i] += adv[i];
        }
    }

    for (int p = 0; p < P; ++p) {
        __syncthreads();
        if (p + 1 < P) {
            char* d = smem + ((p + 1) & 1) * BUF_SZ + tid * 16;
            #pragma unroll
            for (int i = 0; i < 8; ++i) {
                gload_lds16(srcp[i], d + i * 4096);
                srcp[i] += adv[i];
            }
        }
        const char* base = smem + (p & 1) * BUF_SZ;
        #pragma unroll
        for (int g = 0; g < 2; ++g) {
            i32x8 A[4];
            #pragma unroll
            for (int mt = 0; mt < 4; ++mt) {
                const char* pa = base + awmx + g * 8192 + mt * 256;
                U2 u{*(const u32x4*)pa, *(const u32x4*)(pa + 1024)};
                A[mt] = __builtin_bit_cast(i32x8, u);
            }
            #pragma unroll
            for (int nt = 0; nt < 4; ++nt) {
                const char* pb = base + abase + mxo[g] + nt * 160;
                L4 l{*(const long*)pb, *(const long*)(pb + 2880),
                     *(const long*)(pb + 5760), *(const long*)(pb + 8640)};
                i32x8 B = __builtin_bit_cast(i32x8, l);
                #pragma unroll
                for (int mt = 0; mt < 4; ++mt)
                    acc[mt][nt] = __builtin_amdgcn_mfma_scale_f32_16x16x128_f8f6f4(
                        A[mt], B, acc[mt][nt], 0, 0,
                        0, 0x7F7F7F7F, 0, 0x7F7F7F7F);
            }
        }
        {
            long A8[4], B8[4];
            #pragma unroll
            for (int mt = 0; mt < 4; ++mt)
                A8[mt] = *(const long*)(base + aw8 + mt * 256);
            #pragma unroll
            for (int nt = 0; nt < 4; ++nt)
                B8[nt] = *(const long*)(base + ab8 + nt * 160);
            #pragma unroll
            for (int mt = 0; mt < 4; ++mt)
                #pragma unroll
                for (int nt = 0; nt < 4; ++nt)
                    acc[mt][nt] = __builtin_amdgcn_mfma_f32_16x16x32_fp8_fp8(
                        A8[mt], B8[nt], acc[mt][nt], 0, 0, 0);
        }
    }

    // EPI0: planar fp8 store
    #pragma unroll
    for (int nt = 0; nt < 4; ++nt) {
        const int y = y0 + wn * 4 + nt;
        #pragma unroll
        for (int mt = 0; mt < 4; ++mt) {
            const int cb = co0 + mt * 16 + kq * 4;
            const f32x4 bv = *(const f32x4*)(bias + cb);
            float v[4];
            #pragma unroll
            for (int r = 0; r < 4; ++r) v[r] = fmaxf(acc[mt][nt][r] + bv[r], 0.f);
            int w0 = __builtin_amdgcn_cvt_pk_fp8_f32(v[0], v[1], 0, false);
            w0 = __builtin_amdgcn_cvt_pk_fp8_f32(v[2], v[3], w0, true);
            *(int*)(out + (((size_t)img * (CO >> 3) + (cb >> 3)) * HW +
                           (size_t)y * W + x0 + xl) * 8 + (cb & 7)) = w0;
        }
    }
}

// ---------------------------------------------------------------------------
// conv4 DUAL (R14-proven): 16 dbuf phases (8 sr + 8 hr), pass-boundary pointer
// fixup, sr features banked in sacc, fused perceptual epilogue. No F buffer.
// ---------------------------------------------------------------------------
__global__ __launch_bounds__(256, 2) void conv4_dual(
    const u8* __restrict__ in,       // planar fp8, sr imgs then hr imgs
    const u8* __restrict__ wb,
    const float* __restrict__ bias,
    const float* __restrict__ zbuf,
    long hrFix,                      // (nb-1) * 4194304
    float* __restrict__ pacc) {
    const int H = 128, W = 128, CO = 256;
    const size_t HW = 16384;
    const int tid  = threadIdx.x;
    const int lane = tid & 63;
    const int wn   = tid >> 6;
    const int xl = lane & 15;
    const int kq = lane >> 4;
    const int x0 = blockIdx.x * 16;
    const int y0 = blockIdx.y * 16;
    const int img = blockIdx.z >> 2;
    const int co0 = (blockIdx.z & 3) << 6;

    __shared__ __align__(16) char smem[2 * BUF_SZ];

    f32x4 acc[4][4], sacc[4][4];
    #pragma unroll
    for (int m = 0; m < 4; ++m)
        #pragma unroll
        for (int n = 0; n < 4; ++n) acc[m][n] = (f32x4){0.f, 0.f, 0.f, 0.f};

    const u8* inp = in + (size_t)img * 4194304;   // 32 planes * HW * 8

    const char* srcp[8];
    long adv[8];
    #pragma unroll
    for (int i = 0; i < 8; ++i) {
        int c = tid + i * 256;
        srcp[i] = (const char*)zbuf;
        adv[i] = 0;
        if (c < N_ACT_CH) {
            int g = c / 180, r = c - g * 180;
            int row = r / 10, pp = r - row * 10;
            int gy = y0 - 1 + row, colb = x0 - 2 + pp * 2;
            if ((unsigned)gy < (unsigned)H && (unsigned)colb < (unsigned)(W - 1)) {
                srcp[i] = (const char*)(inp + ((size_t)g * HW + (size_t)gy * W + colb) * 8);
                adv[i] = 4 * HW * 8;              // 524288
            }
        } else if (c < N_CHUNK) {
            int c2 = c - N_ACT_CH;
            size_t o;
            if (c2 < 1024) {
                int gt = c2 >> 6, co = c2 & 63;
                o = ((size_t)gt * CO + co0 + co) * 16;
            } else {
                int c3 = c2 - 1024;
                int q = c3 >> 6, co = c3 & 63;
                o = 256 * (size_t)CO + ((size_t)q * CO + co0 + co) * 16;
            }
            srcp[i] = (const char*)(wb + o);
            adv[i] = 288 * (size_t)CO;            // 73728
        }
    }

    int mxo[2];
    #pragma unroll
    for (int g = 0; g < 2; ++g) {
        int t = g * 4 + kq;
        int dy = t / 3, dx = t - dy * 3;
        mxo[g] = (dy * 20 + dx) * 8;
    }
    const int abase = ((wn * 4) * 20 + xl + 1) * 8;
    const int awmx  = WT_BOFF + kq * 2048 + xl * 16;
    const int aw8   = WT_BOFF + 16384 + (kq >> 1) * 1024 + xl * 16 + (kq & 1) * 8;
    const int ab8   = kq * 2880 + abase + (2 * 20 + 2) * 8;

    {
        char* d = smem + tid * 16;
        #pragma unroll
        for (int i = 0; i < 8; ++i) {
            gload_lds16(srcp[i], d + i * 4096);
            srcp[i] += adv[i];
        }
    }

    for (int pp = 0; pp < 16; ++pp) {
        __syncthreads();
        if (pp + 1 < 16) {
            if (pp + 1 == 8) {                    // pass boundary fixup
                #pragma unroll
                for (int i = 0; i < 8; ++i) {
                    if (adv[i] == 524288) srcp[i] += hrFix;
                    else if (adv[i])      srcp[i] -= 8 * 73728;
                }
            }
            char* d = smem + ((pp + 1) & 1) * BUF_SZ + tid * 16;
            #pragma unroll
            for (int i = 0; i < 8; ++i) {
                gload_lds16(srcp[i], d + i * 4096);
                srcp[i] += adv[i];
            }
        }
        const char* base = smem + (pp & 1) * BUF_SZ;
        #pragma unroll
        for (int g = 0; g < 2; ++g) {
            i32x8 A[4];
            #pragma unroll
            for (int mt = 0; mt < 4; ++mt) {
                const char* pa = base + awmx + g * 8192 + mt * 256;
                U2 u{*(const u32x4*)pa, *(const u32x4*)(pa + 1024)};
                A[mt] = __builtin_bit_cast(i32x8, u);
            }
            #pragma unroll
            for (int nt = 0; nt < 4; ++nt) {
                const char* pb = base + abase + mxo[g] + nt * 160;
                L4 l{*(const long*)pb, *(const long*)(pb + 2880),
                     *(const long*)(pb + 5760), *(const long*)(pb + 8640)};
                i32x8 B = __builtin_bit_cast(i32x8, l);
                #pragma unroll
                for (int mt = 0; mt < 4; ++mt)
                    acc[mt][nt] = __builtin_amdgcn_mfma_scale_f32_16x16x128_f8f6f4(
                        A[mt], B, acc[mt][nt], 0, 0,
                        0, 0x7F7F7F7F, 0, 0x7F7F7F7F);
            }
        }
        {
            long A8[4], B8[4];
            #pragma unroll
            for (int mt = 0; mt < 4; ++mt)
                A8[mt] = *(const long*)(base + aw8 + mt * 256);
            #pragma unroll
            for (int nt = 0; nt < 4; ++nt)
                B8[nt] = *(const long*)(base + ab8 + nt * 160);
            #pragma unroll
            for (int mt = 0; mt < 4; ++mt)
                #pragma unroll
                for (int nt = 0; nt < 4; ++nt)
                    acc[mt][nt] = __builtin_amdgcn_mfma_f32_16x16x32_fp8_fp8(
                        A8[mt], B8[nt], acc[mt][nt], 0, 0, 0);
        }
        if (pp == 7) {                             // bank sr features
            #pragma unroll
            for (int mt = 0; mt < 4; ++mt) {
                const int cb = co0 + mt * 16 + kq * 4;
                const f32x4 bv = *(const f32x4*)(bias + cb);
                #pragma unroll
                for (int nt = 0; nt < 4; ++nt) {
                    #pragma unroll
                    for (int r = 0; r < 4; ++r) {
                        sacc[mt][nt][r] = fmaxf(acc[mt][nt][r] + bv[r], 0.f);
                        acc[mt][nt][r] = 0.f;
                    }
                }
            }
        }
    }

    // perceptual partial
    float s = 0.f;
    #pragma unroll
    for (int mt = 0; mt < 4; ++mt) {
        const int cb = co0 + mt * 16 + kq * 4;
        const f32x4 bv = *(const f32x4*)(bias + cb);
        #pragma unroll
        for (int nt = 0; nt < 4; ++nt) {
            #pragma unroll
            for (int r = 0; r < 4; ++r) {
                float v = fmaxf(acc[mt][nt][r] + bv[r], 0.f);
                float d = sacc[mt][nt][r] - v;
                s += d * d;
            }
        }
    }
    #pragma unroll
    for (int o = 32; o > 0; o >>= 1) s += __shfl_down(s, o, 64);
    __syncthreads();
    if (lane == 0) *(float*)(smem + wn * 4) = s;
    __syncthreads();
    if (tid == 0) {
        float tot = *(float*)(smem) + *(float*)(smem + 4) +
                    *(float*)(smem + 8) + *(float*)(smem + 12);
        atomicAdd(pacc, tot);
    }
}

// ---------------------------------------------------------------------------
// launch
// ---------------------------------------------------------------------------
extern "C" void kernel_launch(void* const* d_in, const int* in_sizes, int n_in,
                              void* d_out, int out_size, void* d_ws, size_t ws_size,
                              hipStream_t stream) {
    const float* sr = (const float*)d_in[0];
    const float* hr = (const float*)d_in[1];
    const float* w1 = (const float*)d_in[2];
    const float* b1 = (const float*)d_in[3];
    const float* w2 = (const float*)d_in[4];
    const float* b2 = (const float*)d_in[5];
    const float* w3 = (const float*)d_in[6];
    const float* b3 = (const float*)d_in[7];
    const float* w4 = (const float*)d_in[8];
    const float* b4 = (const float*)d_in[9];
    float* out = (float*)d_out;

    char* ws = (char*)d_ws;
    size_t off = 0;
    float* accs = (float*)(ws + off); off += 256;
    float* zbuf = (float*)(ws + off); off += 256;
    u8* wb2 = (u8*)(ws + off); off += (size_t)128 * 9 * 64;
    u8* wb3 = (u8*)(ws + off); off += (size_t)256 * 9 * 128;
    u8* wb4 = (u8*)(ws + off); off += (size_t)256 * 9 * 256;
    const size_t fixed = (off + 255) & ~(size_t)255;

    const size_t MB = 1024u * 1024u;
    // per batch-image pair (sr+hr): A 8MB, P 4MB = 12MB
    int nb = 8;
    while (nb > 1 && fixed + (size_t)nb * 12 * MB > ws_size) nb >>= 1;

    u8* A = (u8*)(ws + fixed);                          // fp8 planar (conv1 out / conv3 out)
    u8* P = (u8*)(ws + fixed + (size_t)nb * 8 * MB);    // fp8 planar pooled

    hipMemsetAsync(ws, 0, 512, stream);                 // accs + zbuf
    prep_loss_kernel<<<6216, 256, 0, stream>>>(w2, wb2, w3, wb3, w4, wb4, sr, hr, accs);

    for (int b0 = 0; b0 < 8; b0 += nb) {
        const int ni = 2 * nb;   // sr images then hr images
        // conv1 (sr+hr merged) -> A
        conv1_kernel<<<dim3(256, ni), 256, 0, stream>>>(sr, hr, nb, b0, w1, b1, A);
        // conv2 + fused pool, single-stage (merged) -> P
        conv2_ss<<<dim3(16, 16, ni * 2), 256, 0, stream>>>(A, wb2, b2, P, zbuf);
        // conv3 (merged) -> A (reuse)
        conv_mx<128, 0><<<dim3(8, 8, ni * 4), 256, 0, stream>>>(
            P, wb3, b3, A, 128, 128, 256, zbuf);
        // conv4 dual-pass: sr + hr + fused perceptual, F never materialized
        conv4_dual<<<dim3(8, 8, nb * 4), 256, 0, stream>>>(
            A, wb4, b4, zbuf, (long)(nb - 1) * 4194304, accs + 2);
    }

    finalize_kernel<<<1, 1, 0, stream>>>(accs, out);
}